// Round 1
// baseline (8427.316 us; speedup 1.0000x reference)
//
#include <hip/hip_runtime.h>
#include <hip/hip_bf16.h>

#define N_NODES   50000
#define F         128
#define NGRAPH    64

// ---------------------------------------------------------------- degree
__global__ __launch_bounds__(256) void deg_kernel(const int* __restrict__ dst,
                                                  float* __restrict__ deg, int nE) {
    int e = blockIdx.x * 256 + threadIdx.x;
    if (e < nE) atomicAdd(&deg[dst[e]], 1.0f);
}

__global__ __launch_bounds__(256) void invdeg_kernel(float* __restrict__ deg, int n) {
    int i = blockIdx.x * 256 + threadIdx.x;
    if (i < n) deg[i] = 1.0f / fmaxf(deg[i], 1.0f);
}

// ---------------------------------------------------------------- scatter: agg[dst] += h[src]
// 32 lanes per edge, each lane handles 4 contiguous floats (float4 read, 4 atomics)
__global__ __launch_bounds__(256) void scatter_kernel(const float* __restrict__ xin,
                                                      const int* __restrict__ src,
                                                      const int* __restrict__ dst,
                                                      float* __restrict__ agg, int nE) {
    long tid  = (long)blockIdx.x * 256 + threadIdx.x;
    long e    = tid >> 5;
    if (e >= nE) return;
    int lane  = (int)(tid & 31);
    int s = src[e], d = dst[e];
    const float4 v = *(const float4*)(xin + (long)s * F + lane * 4);
    float* o = agg + (long)d * F + lane * 4;
    atomicAdd(o + 0, v.x);
    atomicAdd(o + 1, v.y);
    atomicAdd(o + 2, v.z);
    atomicAdd(o + 3, v.w);
}

// ---------------------------------------------------------------- fused SAGE layer GEMM
// hout = relu( (agg * inv_deg) @ Wl + hin @ Wr + b )
// Treated as one M x 256 x 128 GEMM with A = [agg*idg | hin], W = [Wl ; Wr].
// Block: 256 threads, tile 64 rows x 128 cols, each thread 8 rows x 4 cols.
__global__ __launch_bounds__(256) void sage_gemm(const float* __restrict__ agg,
                                                 const float* __restrict__ inv_deg,
                                                 const float* __restrict__ hin,
                                                 const float* __restrict__ Wl,
                                                 const float* __restrict__ Wr,
                                                 const float* __restrict__ bias,
                                                 float* __restrict__ hout, int n_nodes) {
    __shared__ float sA[64][65];    // 64 rows x 64 k (+1 pad)
    __shared__ float sW[64][128];   // 64 k x 128 cols

    const int tid  = threadIdx.x;
    const int row0 = blockIdx.x * 64;
    const int tn   = tid & 31;   // cols tn*4 .. tn*4+3
    const int tm   = tid >> 5;   // rows tm*8 .. tm*8+7

    float acc[8][4] = {};

    for (int kc = 0; kc < 256; kc += 64) {
        // ---- stage W chunk: rows kc..kc+63 of concat(Wl;Wr)
        {
            const float* Wsrc = (kc < 128) ? (Wl + kc * F) : (Wr + (kc - 128) * F);
            for (int idx = tid; idx < 64 * 32; idx += 256) {
                int r = idx >> 5, c4 = idx & 31;
                float4 v = ((const float4*)(Wsrc + r * F))[c4];
                ((float4*)&sW[r][0])[c4] = v;
            }
        }
        // ---- stage A chunk: 64 rows x 64 k
        {
            for (int idx = tid; idx < 64 * 16; idx += 256) {
                int r  = idx >> 4;
                int c4 = idx & 15;          // k offset = c4*4 within chunk
                int m  = row0 + r;
                float4 v = make_float4(0.f, 0.f, 0.f, 0.f);
                if (m < n_nodes) {
                    if (kc < 128) {
                        v = ((const float4*)(agg + (long)m * F + kc))[c4];
                        float idg = inv_deg[m];
                        v.x *= idg; v.y *= idg; v.z *= idg; v.w *= idg;
                    } else {
                        v = ((const float4*)(hin + (long)m * F + (kc - 128)))[c4];
                    }
                }
                sA[r][c4 * 4 + 0] = v.x;
                sA[r][c4 * 4 + 1] = v.y;
                sA[r][c4 * 4 + 2] = v.z;
                sA[r][c4 * 4 + 3] = v.w;
            }
        }
        __syncthreads();

        #pragma unroll 16
        for (int k = 0; k < 64; ++k) {
            float4 w = ((const float4*)&sW[k][0])[tn];
            #pragma unroll
            for (int i = 0; i < 8; ++i) {
                float a = sA[tm * 8 + i][k];
                acc[i][0] += a * w.x;
                acc[i][1] += a * w.y;
                acc[i][2] += a * w.z;
                acc[i][3] += a * w.w;
            }
        }
        __syncthreads();
    }

    float4 bv = ((const float4*)bias)[tn];
    #pragma unroll
    for (int i = 0; i < 8; ++i) {
        int m = row0 + tm * 8 + i;
        if (m < n_nodes) {
            float4 o;
            o.x = fmaxf(acc[i][0] + bv.x, 0.f);
            o.y = fmaxf(acc[i][1] + bv.y, 0.f);
            o.z = fmaxf(acc[i][2] + bv.z, 0.f);
            o.w = fmaxf(acc[i][3] + bv.w, 0.f);
            ((float4*)(hout + (long)m * F))[tn] = o;
        }
    }
}

// ---------------------------------------------------------------- pooling (batch sorted)
// 128 nodes per block, 128 threads (one per feature). Run-length accumulate, flush on
// graph change. Max via unsigned-bit atomicMax (all values >= 0 post-relu).
__global__ __launch_bounds__(128) void pool_kernel(const float* __restrict__ h,
                                                   const int* __restrict__ batch,
                                                   float* __restrict__ add_p,
                                                   unsigned* __restrict__ max_p,
                                                   float* __restrict__ cnt, int n) {
    int start = blockIdx.x * 128;
    if (start >= n) return;
    int end = min(start + 128, n);
    int c = threadIdx.x;

    float s = 0.f, mx = 0.f, ct = 0.f;
    int g = batch[start];
    for (int m = start; m < end; ++m) {
        int gm = batch[m];
        if (gm != g) {
            atomicAdd(&add_p[g * F + c], s);
            atomicMax(&max_p[g * F + c], __float_as_uint(mx));
            if (c == 0) atomicAdd(&cnt[g], ct);
            s = 0.f; mx = 0.f; ct = 0.f; g = gm;
        }
        float v = h[(long)m * F + c];
        s += v;
        mx = fmaxf(mx, v);
        ct += 1.f;
    }
    atomicAdd(&add_p[g * F + c], s);
    atomicMax(&max_p[g * F + c], __float_as_uint(mx));
    if (c == 0) atomicAdd(&cnt[g], ct);
}

// ---------------------------------------------------------------- head MLP + log_softmax
__global__ __launch_bounds__(128) void head_kernel(const float* __restrict__ add_p,
                                                   const float* __restrict__ cnt,
                                                   const unsigned* __restrict__ max_p,
                                                   const float* __restrict__ W1,
                                                   const float* __restrict__ b1,
                                                   const float* __restrict__ W2,
                                                   const float* __restrict__ b2,
                                                   float* __restrict__ out) {
    int g = blockIdx.x, n = threadIdx.x;
    __shared__ float gv[384];
    float a    = add_p[g * F + n];
    float invc = 1.f / fmaxf(cnt[g], 1.f);
    gv[n]       = a;
    gv[128 + n] = a * invc;
    gv[256 + n] = __uint_as_float(max_p[g * F + n]);
    __syncthreads();

    float acc = b1[n];
    #pragma unroll 8
    for (int k = 0; k < 384; ++k) acc += gv[k] * W1[k * F + n];
    float r = fmaxf(acc, 0.f);

    float l0 = r * W2[n * 2 + 0];
    float l1 = r * W2[n * 2 + 1];
    #pragma unroll
    for (int off = 32; off > 0; off >>= 1) {
        l0 += __shfl_down(l0, off);
        l1 += __shfl_down(l1, off);
    }
    __shared__ float part[4];
    if ((n & 63) == 0) { part[(n >> 6) * 2] = l0; part[(n >> 6) * 2 + 1] = l1; }
    __syncthreads();
    if (n == 0) {
        float L0 = part[0] + part[2] + b2[0];
        float L1 = part[1] + part[3] + b2[1];
        float m  = fmaxf(L0, L1);
        float lse = m + logf(expf(L0 - m) + expf(L1 - m));
        out[g * 2 + 0] = L0 - lse;
        out[g * 2 + 1] = L1 - lse;
    }
}

// ---------------------------------------------------------------- launch
extern "C" void kernel_launch(void* const* d_in, const int* in_sizes, int n_in,
                              void* d_out, int out_size, void* d_ws, size_t ws_size,
                              hipStream_t stream) {
    const float* x     = (const float*)d_in[0];
    const int*   ei    = (const int*)d_in[1];
    const int*   batch = (const int*)d_in[2];
    const float* Wl0 = (const float*)d_in[3];
    const float* Wr0 = (const float*)d_in[4];
    const float* b0  = (const float*)d_in[5];
    const float* Wl1 = (const float*)d_in[6];
    const float* Wr1 = (const float*)d_in[7];
    const float* b1  = (const float*)d_in[8];
    const float* Wl2 = (const float*)d_in[9];
    const float* Wr2 = (const float*)d_in[10];
    const float* b2  = (const float*)d_in[11];
    const float* W_lin1 = (const float*)d_in[12];
    const float* b_lin1 = (const float*)d_in[13];
    const float* W_lin2 = (const float*)d_in[14];
    const float* b_lin2 = (const float*)d_in[15];

    const int nE = in_sizes[1] / 2;
    const int* src = ei;
    const int* dst = ei + nE;

    // workspace layout (floats)
    float* ws       = (float*)d_ws;
    float* inv_deg  = ws;                          // 50048
    float* agg      = ws + 50048;                  // 6,400,000
    float* hA       = agg + (long)N_NODES * F;     // 6,400,000
    float* hB       = hA + (long)N_NODES * F;      // 6,400,000
    float* add_p    = hB + (long)N_NODES * F;      // 8192
    unsigned* max_p = (unsigned*)(add_p + NGRAPH * F); // 8192
    float* cnt      = (float*)(max_p + NGRAPH * F);    // 64

    const long aggBytes = (long)N_NODES * F * sizeof(float);
    const int gridE   = (nE + 255) / 256;
    const int gridS   = (int)(((long)nE * 32 + 255) / 256);
    const int gridG   = (N_NODES + 63) / 64;
    const int gridN   = (N_NODES + 255) / 256;
    const int gridP   = (N_NODES + 127) / 128;

    // degree (shared by all layers)
    hipMemsetAsync(inv_deg, 0, N_NODES * sizeof(float), stream);
    deg_kernel<<<gridE, 256, 0, stream>>>(dst, inv_deg, nE);
    invdeg_kernel<<<gridN, 256, 0, stream>>>(inv_deg, N_NODES);

    // layer 0: x -> hA
    hipMemsetAsync(agg, 0, aggBytes, stream);
    scatter_kernel<<<gridS, 256, 0, stream>>>(x, src, dst, agg, nE);
    sage_gemm<<<gridG, 256, 0, stream>>>(agg, inv_deg, x, Wl0, Wr0, b0, hA, N_NODES);

    // layer 1: hA -> hB
    hipMemsetAsync(agg, 0, aggBytes, stream);
    scatter_kernel<<<gridS, 256, 0, stream>>>(hA, src, dst, agg, nE);
    sage_gemm<<<gridG, 256, 0, stream>>>(agg, inv_deg, hA, Wl1, Wr1, b1, hB, N_NODES);

    // layer 2: hB -> hA
    hipMemsetAsync(agg, 0, aggBytes, stream);
    scatter_kernel<<<gridS, 256, 0, stream>>>(hB, src, dst, agg, nE);
    sage_gemm<<<gridG, 256, 0, stream>>>(agg, inv_deg, hB, Wl2, Wr2, b2, hA, N_NODES);

    // pooling
    hipMemsetAsync(add_p, 0, (NGRAPH * F * 2 + NGRAPH) * sizeof(float), stream);
    pool_kernel<<<gridP, 128, 0, stream>>>(hA, batch, add_p, max_p, cnt, N_NODES);

    // head
    head_kernel<<<NGRAPH, 128, 0, stream>>>(add_p, cnt, max_p,
                                            W_lin1, b_lin1, W_lin2, b_lin2,
                                            (float*)d_out);
}

// Round 2
// 957.440 us; speedup vs baseline: 8.8019x; 8.8019x over previous
//
#include <hip/hip_runtime.h>
#include <hip/hip_bf16.h>

#define N_NODES   50000
#define F         128
#define NGRAPH    64

// ---------------------------------------------------------------- degree histogram (int)
__global__ __launch_bounds__(256) void deg_kernel(const int* __restrict__ dst,
                                                  int* __restrict__ deg, int nE) {
    int e = blockIdx.x * 256 + threadIdx.x;
    if (e < nE) atomicAdd(&deg[dst[e]], 1);
}

// ---------------------------------------------------------------- exclusive scan (single block)
// n = 50000, 1024 threads, 49 elems/thread serial + Hillis-Steele block scan.
__global__ __launch_bounds__(1024) void scan_kernel(const int* __restrict__ deg,
                                                    int* __restrict__ row_ptr,
                                                    int* __restrict__ cursor, int n) {
    __shared__ int part[1024];
    const int t = threadIdx.x;
    const int C = (N_NODES + 1023) >> 10;   // 49
    const int c0 = t * C;

    int sum = 0;
    for (int i = 0; i < C; ++i) {
        int idx = c0 + i;
        if (idx < n) sum += deg[idx];
    }
    part[t] = sum;
    __syncthreads();
    for (int off = 1; off < 1024; off <<= 1) {
        int v = (t >= off) ? part[t - off] : 0;
        __syncthreads();
        part[t] += v;
        __syncthreads();
    }
    int run = (t == 0) ? 0 : part[t - 1];
    for (int i = 0; i < C; ++i) {
        int idx = c0 + i;
        if (idx < n) {
            row_ptr[idx] = run;
            cursor[idx]  = run;
            run += deg[idx];
        }
    }
    if (t == 1023) row_ptr[n] = run;
}

// ---------------------------------------------------------------- CSR edge placement
__global__ __launch_bounds__(256) void place_kernel(const int* __restrict__ src,
                                                    const int* __restrict__ dst,
                                                    int* __restrict__ cursor,
                                                    int* __restrict__ csr_src, int nE) {
    int e = blockIdx.x * 256 + threadIdx.x;
    if (e >= nE) return;
    int p = atomicAdd(&cursor[dst[e]], 1);
    csr_src[p] = src[e];
}

// ---------------------------------------------------------------- gather-mean aggregation
// One wave (64 lanes) per destination node; lane owns 2 floats of the 128-float row.
__global__ __launch_bounds__(256) void gather_kernel(const float* __restrict__ xin,
                                                     const int* __restrict__ row_ptr,
                                                     const int* __restrict__ csr_src,
                                                     float* __restrict__ agg, int n) {
    int node = blockIdx.x * 4 + (threadIdx.x >> 6);
    if (node >= n) return;
    int lane = threadIdx.x & 63;

    const float2* __restrict__ xr = (const float2*)xin;
    int beg = row_ptr[node], end = row_ptr[node + 1];

    float2 a0 = {0.f, 0.f}, a1 = {0.f, 0.f}, a2 = {0.f, 0.f}, a3 = {0.f, 0.f};
    int i = beg;
    for (; i + 3 < end; i += 4) {
        int s0 = csr_src[i + 0], s1 = csr_src[i + 1];
        int s2 = csr_src[i + 2], s3 = csr_src[i + 3];
        float2 v0 = xr[(long)s0 * 64 + lane];
        float2 v1 = xr[(long)s1 * 64 + lane];
        float2 v2 = xr[(long)s2 * 64 + lane];
        float2 v3 = xr[(long)s3 * 64 + lane];
        a0.x += v0.x; a0.y += v0.y;
        a1.x += v1.x; a1.y += v1.y;
        a2.x += v2.x; a2.y += v2.y;
        a3.x += v3.x; a3.y += v3.y;
    }
    for (; i < end; ++i) {
        int s0 = csr_src[i];
        float2 v0 = xr[(long)s0 * 64 + lane];
        a0.x += v0.x; a0.y += v0.y;
    }
    float inv = 1.f / fmaxf((float)(end - beg), 1.f);
    float2 s;
    s.x = (a0.x + a1.x + a2.x + a3.x) * inv;
    s.y = (a0.y + a1.y + a2.y + a3.y) * inv;
    ((float2*)(agg + (long)node * F))[lane] = s;
}

// ---------------------------------------------------------------- fused SAGE layer GEMM
// hout = relu( agg @ Wl + hin @ Wr + b );  agg already mean-normalized.
__global__ __launch_bounds__(256) void sage_gemm(const float* __restrict__ agg,
                                                 const float* __restrict__ hin,
                                                 const float* __restrict__ Wl,
                                                 const float* __restrict__ Wr,
                                                 const float* __restrict__ bias,
                                                 float* __restrict__ hout, int n_nodes) {
    __shared__ float sA[64][65];
    __shared__ float sW[64][128];

    const int tid  = threadIdx.x;
    const int row0 = blockIdx.x * 64;
    const int tn   = tid & 31;
    const int tm   = tid >> 5;

    float acc[8][4] = {};

    for (int kc = 0; kc < 256; kc += 64) {
        const float* Wsrc = (kc < 128) ? (Wl + kc * F) : (Wr + (kc - 128) * F);
        for (int idx = tid; idx < 64 * 32; idx += 256) {
            int r = idx >> 5, c4 = idx & 31;
            float4 v = ((const float4*)(Wsrc + r * F))[c4];
            ((float4*)&sW[r][0])[c4] = v;
        }
        const float* Asrc = (kc < 128) ? (agg + kc) : (hin + (kc - 128));
        for (int idx = tid; idx < 64 * 16; idx += 256) {
            int r  = idx >> 4;
            int c4 = idx & 15;
            int m  = row0 + r;
            float4 v = make_float4(0.f, 0.f, 0.f, 0.f);
            if (m < n_nodes) v = ((const float4*)(Asrc + (long)m * F))[c4];
            sA[r][c4 * 4 + 0] = v.x;
            sA[r][c4 * 4 + 1] = v.y;
            sA[r][c4 * 4 + 2] = v.z;
            sA[r][c4 * 4 + 3] = v.w;
        }
        __syncthreads();

        #pragma unroll 16
        for (int k = 0; k < 64; ++k) {
            float4 w = ((const float4*)&sW[k][0])[tn];
            #pragma unroll
            for (int i = 0; i < 8; ++i) {
                float a = sA[tm * 8 + i][k];
                acc[i][0] += a * w.x;
                acc[i][1] += a * w.y;
                acc[i][2] += a * w.z;
                acc[i][3] += a * w.w;
            }
        }
        __syncthreads();
    }

    float4 bv = ((const float4*)bias)[tn];
    #pragma unroll
    for (int i = 0; i < 8; ++i) {
        int m = row0 + tm * 8 + i;
        if (m < n_nodes) {
            float4 o;
            o.x = fmaxf(acc[i][0] + bv.x, 0.f);
            o.y = fmaxf(acc[i][1] + bv.y, 0.f);
            o.z = fmaxf(acc[i][2] + bv.z, 0.f);
            o.w = fmaxf(acc[i][3] + bv.w, 0.f);
            ((float4*)(hout + (long)m * F))[tn] = o;
        }
    }
}

// ---------------------------------------------------------------- pooling (batch sorted)
__global__ __launch_bounds__(128) void pool_kernel(const float* __restrict__ h,
                                                   const int* __restrict__ batch,
                                                   float* __restrict__ add_p,
                                                   unsigned* __restrict__ max_p,
                                                   float* __restrict__ cnt, int n) {
    int start = blockIdx.x * 128;
    if (start >= n) return;
    int end = min(start + 128, n);
    int c = threadIdx.x;

    float s = 0.f, mx = 0.f, ct = 0.f;
    int g = batch[start];
    for (int m = start; m < end; ++m) {
        int gm = batch[m];
        if (gm != g) {
            atomicAdd(&add_p[g * F + c], s);
            atomicMax(&max_p[g * F + c], __float_as_uint(mx));
            if (c == 0) atomicAdd(&cnt[g], ct);
            s = 0.f; mx = 0.f; ct = 0.f; g = gm;
        }
        float v = h[(long)m * F + c];
        s += v;
        mx = fmaxf(mx, v);
        ct += 1.f;
    }
    atomicAdd(&add_p[g * F + c], s);
    atomicMax(&max_p[g * F + c], __float_as_uint(mx));
    if (c == 0) atomicAdd(&cnt[g], ct);
}

// ---------------------------------------------------------------- head MLP + log_softmax
__global__ __launch_bounds__(128) void head_kernel(const float* __restrict__ add_p,
                                                   const float* __restrict__ cnt,
                                                   const unsigned* __restrict__ max_p,
                                                   const float* __restrict__ W1,
                                                   const float* __restrict__ b1,
                                                   const float* __restrict__ W2,
                                                   const float* __restrict__ b2,
                                                   float* __restrict__ out) {
    int g = blockIdx.x, n = threadIdx.x;
    __shared__ float gv[384];
    float a    = add_p[g * F + n];
    float invc = 1.f / fmaxf(cnt[g], 1.f);
    gv[n]       = a;
    gv[128 + n] = a * invc;
    gv[256 + n] = __uint_as_float(max_p[g * F + n]);
    __syncthreads();

    float acc = b1[n];
    #pragma unroll 8
    for (int k = 0; k < 384; ++k) acc += gv[k] * W1[k * F + n];
    float r = fmaxf(acc, 0.f);

    float l0 = r * W2[n * 2 + 0];
    float l1 = r * W2[n * 2 + 1];
    #pragma unroll
    for (int off = 32; off > 0; off >>= 1) {
        l0 += __shfl_down(l0, off);
        l1 += __shfl_down(l1, off);
    }
    __shared__ float part[4];
    if ((n & 63) == 0) { part[(n >> 6) * 2] = l0; part[(n >> 6) * 2 + 1] = l1; }
    __syncthreads();
    if (n == 0) {
        float L0 = part[0] + part[2] + b2[0];
        float L1 = part[1] + part[3] + b2[1];
        float m  = fmaxf(L0, L1);
        float lse = m + logf(expf(L0 - m) + expf(L1 - m));
        out[g * 2 + 0] = L0 - lse;
        out[g * 2 + 1] = L1 - lse;
    }
}

// ---------------------------------------------------------------- launch
extern "C" void kernel_launch(void* const* d_in, const int* in_sizes, int n_in,
                              void* d_out, int out_size, void* d_ws, size_t ws_size,
                              hipStream_t stream) {
    const float* x     = (const float*)d_in[0];
    const int*   ei    = (const int*)d_in[1];
    const int*   batch = (const int*)d_in[2];
    const float* Wl0 = (const float*)d_in[3];
    const float* Wr0 = (const float*)d_in[4];
    const float* b0  = (const float*)d_in[5];
    const float* Wl1 = (const float*)d_in[6];
    const float* Wr1 = (const float*)d_in[7];
    const float* b1  = (const float*)d_in[8];
    const float* Wl2 = (const float*)d_in[9];
    const float* Wr2 = (const float*)d_in[10];
    const float* b2  = (const float*)d_in[11];
    const float* W_lin1 = (const float*)d_in[12];
    const float* b_lin1 = (const float*)d_in[13];
    const float* W_lin2 = (const float*)d_in[14];
    const float* b_lin2 = (const float*)d_in[15];

    const int nE = in_sizes[1] / 2;
    const int* src = ei;
    const int* dst = ei + nE;

    // workspace layout
    int*   deg     = (int*)d_ws;                       // 50000
    int*   row_ptr = deg + N_NODES;                    // 50001
    int*   cursor  = row_ptr + N_NODES + 1;            // 50000
    int*   csr_src = cursor + N_NODES;                 // nE
    float* agg     = (float*)(csr_src + nE);           // 6.4M
    float* hA      = agg + (long)N_NODES * F;          // 6.4M
    float* hB      = hA + (long)N_NODES * F;           // 6.4M
    float* add_p   = hB + (long)N_NODES * F;           // 8192
    unsigned* max_p = (unsigned*)(add_p + NGRAPH * F); // 8192
    float* cnt     = (float*)(max_p + NGRAPH * F);     // 64

    const int gridE = (nE + 255) / 256;
    const int gridG = (N_NODES + 63) / 64;
    const int gridW = (N_NODES + 3) / 4;       // gather: 4 waves/block
    const int gridP = (N_NODES + 127) / 128;

    // ---- CSR build (once, reused by all 3 layers)
    hipMemsetAsync(deg, 0, N_NODES * sizeof(int), stream);
    deg_kernel<<<gridE, 256, 0, stream>>>(dst, deg, nE);
    scan_kernel<<<1, 1024, 0, stream>>>(deg, row_ptr, cursor, N_NODES);
    place_kernel<<<gridE, 256, 0, stream>>>(src, dst, cursor, csr_src, nE);

    // ---- layer 0: x -> hA
    gather_kernel<<<gridW, 256, 0, stream>>>(x, row_ptr, csr_src, agg, N_NODES);
    sage_gemm<<<gridG, 256, 0, stream>>>(agg, x, Wl0, Wr0, b0, hA, N_NODES);

    // ---- layer 1: hA -> hB
    gather_kernel<<<gridW, 256, 0, stream>>>(hA, row_ptr, csr_src, agg, N_NODES);
    sage_gemm<<<gridG, 256, 0, stream>>>(agg, hA, Wl1, Wr1, b1, hB, N_NODES);

    // ---- layer 2: hB -> hA
    gather_kernel<<<gridW, 256, 0, stream>>>(hB, row_ptr, csr_src, agg, N_NODES);
    sage_gemm<<<gridG, 256, 0, stream>>>(agg, hB, Wl2, Wr2, b2, hA, N_NODES);

    // ---- pooling
    hipMemsetAsync(add_p, 0, (NGRAPH * F * 2 + NGRAPH) * sizeof(float), stream);
    pool_kernel<<<gridP, 128, 0, stream>>>(hA, batch, add_p, max_p, cnt, N_NODES);

    // ---- head
    head_kernel<<<NGRAPH, 128, 0, stream>>>(add_p, cnt, max_p,
                                            W_lin1, b_lin1, W_lin2, b_lin2,
                                            (float*)d_out);
}

// Round 3
// 500.482 us; speedup vs baseline: 16.8384x; 1.9130x over previous
//
#include <hip/hip_runtime.h>
#include <hip/hip_bf16.h>

#define N_NODES   50000
#define F         128
#define NGRAPH    64
#define NCHUNK    ((N_NODES + 255) / 256)   // 196

typedef __attribute__((ext_vector_type(8))) short  bf16x8;
typedef __attribute__((ext_vector_type(4))) float  f32x4;

// ---------------------------------------------------------------- degree histogram
__global__ __launch_bounds__(256) void deg_kernel(const int* __restrict__ dst,
                                                  int* __restrict__ deg, int nE) {
    int e = blockIdx.x * 256 + threadIdx.x;
    if (e < nE) atomicAdd(&deg[dst[e]], 1);
}

// ---------------------------------------------------------------- hierarchical scan
__global__ __launch_bounds__(256) void scan_part(const int* __restrict__ deg,
                                                 int* __restrict__ bsum, int n) {
    int i = blockIdx.x * 256 + threadIdx.x;
    int d = (i < n) ? deg[i] : 0;
    #pragma unroll
    for (int off = 32; off > 0; off >>= 1) d += __shfl_down(d, off);
    __shared__ int part[4];
    if ((threadIdx.x & 63) == 0) part[threadIdx.x >> 6] = d;
    __syncthreads();
    if (threadIdx.x == 0) bsum[blockIdx.x] = part[0] + part[1] + part[2] + part[3];
}

__global__ __launch_bounds__(256) void scan_block(const int* __restrict__ bsum,
                                                  int* __restrict__ boff) {
    __shared__ int s[256];
    int t = threadIdx.x;
    int v = (t < NCHUNK) ? bsum[t] : 0;
    s[t] = v;
    __syncthreads();
    for (int off = 1; off < 256; off <<= 1) {
        int u = (t >= off) ? s[t - off] : 0;
        __syncthreads();
        s[t] += u;
        __syncthreads();
    }
    if (t < NCHUNK) boff[t] = s[t] - v;   // exclusive
}

__global__ __launch_bounds__(256) void scan_final(const int* __restrict__ deg,
                                                  const int* __restrict__ boff,
                                                  int* __restrict__ row_ptr,
                                                  int* __restrict__ cursor, int n) {
    __shared__ int s[256];
    int t = threadIdx.x;
    int i = blockIdx.x * 256 + t;
    int d = (i < n) ? deg[i] : 0;
    s[t] = d;
    __syncthreads();
    for (int off = 1; off < 256; off <<= 1) {
        int u = (t >= off) ? s[t - off] : 0;
        __syncthreads();
        s[t] += u;
        __syncthreads();
    }
    if (i < n) {
        int rp = boff[blockIdx.x] + s[t] - d;
        row_ptr[i] = rp;
        cursor[i]  = rp;
        if (i == n - 1) row_ptr[n] = rp + d;
    }
}

// ---------------------------------------------------------------- CSR edge placement
__global__ __launch_bounds__(256) void place_kernel(const int* __restrict__ src,
                                                    const int* __restrict__ dst,
                                                    int* __restrict__ cursor,
                                                    int* __restrict__ csr_src, int nE) {
    int e = blockIdx.x * 256 + threadIdx.x;
    if (e >= nE) return;
    int p = atomicAdd(&cursor[dst[e]], 1);
    csr_src[p] = src[e];
}

// ---------------------------------------------------------------- fp32 -> bf16 convert
struct bh4 { __hip_bfloat16 a, b, c, d; };
__global__ __launch_bounds__(256) void cvt_kernel(const float* __restrict__ in,
                                                  __hip_bfloat16* __restrict__ out, long n4) {
    long i = (long)blockIdx.x * 256 + threadIdx.x;
    if (i >= n4) return;
    float4 v = ((const float4*)in)[i];
    bh4 o;
    o.a = __float2bfloat16(v.x);
    o.b = __float2bfloat16(v.y);
    o.c = __float2bfloat16(v.z);
    o.d = __float2bfloat16(v.w);
    ((bh4*)out)[i] = o;
}

// ---------------------------------------------------------------- gather-mean (bf16 in/out)
// One wave per node; lane owns 2 features (one packed uint per row).
__global__ __launch_bounds__(256) void gather_kernel(const __hip_bfloat16* __restrict__ xin,
                                                     const int* __restrict__ row_ptr,
                                                     const int* __restrict__ csr_src,
                                                     __hip_bfloat16* __restrict__ agg, int n) {
    int node = blockIdx.x * 4 + (threadIdx.x >> 6);
    if (node >= n) return;
    int lane = threadIdx.x & 63;

    const unsigned* __restrict__ xr = (const unsigned*)xin;
    int beg = row_ptr[node], end = row_ptr[node + 1];

    float ax0 = 0.f, ay0 = 0.f, ax1 = 0.f, ay1 = 0.f;
    float ax2 = 0.f, ay2 = 0.f, ax3 = 0.f, ay3 = 0.f;
    int i = beg;
    for (; i + 3 < end; i += 4) {
        unsigned v0 = xr[(long)csr_src[i + 0] * 64 + lane];
        unsigned v1 = xr[(long)csr_src[i + 1] * 64 + lane];
        unsigned v2 = xr[(long)csr_src[i + 2] * 64 + lane];
        unsigned v3 = xr[(long)csr_src[i + 3] * 64 + lane];
        ax0 += __uint_as_float(v0 << 16); ay0 += __uint_as_float(v0 & 0xffff0000u);
        ax1 += __uint_as_float(v1 << 16); ay1 += __uint_as_float(v1 & 0xffff0000u);
        ax2 += __uint_as_float(v2 << 16); ay2 += __uint_as_float(v2 & 0xffff0000u);
        ax3 += __uint_as_float(v3 << 16); ay3 += __uint_as_float(v3 & 0xffff0000u);
    }
    for (; i < end; ++i) {
        unsigned v0 = xr[(long)csr_src[i] * 64 + lane];
        ax0 += __uint_as_float(v0 << 16); ay0 += __uint_as_float(v0 & 0xffff0000u);
    }
    float inv = 1.f / fmaxf((float)(end - beg), 1.f);
    float sx = (ax0 + ax1 + ax2 + ax3) * inv;
    float sy = (ay0 + ay1 + ay2 + ay3) * inv;
    __hip_bfloat162 o;
    o.x = __float2bfloat16(sx);
    o.y = __float2bfloat16(sy);
    ((__hip_bfloat162*)agg)[(long)node * 64 + lane] = o;
}

// ---------------------------------------------------------------- W fragment pre-pack
// Wf[frag=kstep*8+ntile][lane=q*16+r][j] = W[kstep*32+q*8+j][ntile*16+r], W=concat(Wl;Wr)
__global__ __launch_bounds__(256) void wfrag_kernel(const float* __restrict__ Wl,
                                                    const float* __restrict__ Wr,
                                                    __hip_bfloat16* __restrict__ Wf) {
    int t = blockIdx.x * 256 + threadIdx.x;   // 4096 threads
    int frag = t >> 6, lane = t & 63;
    int kstep = frag >> 3, ntg = frag & 7;
    int q = lane >> 4, r = lane & 15;
    short vals[8];
    #pragma unroll
    for (int j = 0; j < 8; ++j) {
        int krow = kstep * 32 + q * 8 + j;
        int col  = ntg * 16 + r;
        float f  = (krow < 128) ? Wl[krow * F + col] : Wr[(krow - 128) * F + col];
        __hip_bfloat16 h = __float2bfloat16(f);
        vals[j] = *(short*)&h;
    }
    bf16x8 v;
    #pragma unroll
    for (int j = 0; j < 8; ++j) v[j] = vals[j];
    ((bf16x8*)Wf)[t] = v;
}

// ---------------------------------------------------------------- MFMA SAGE GEMM
// hout = relu( [agg | hin] @ [Wl;Wr] + b ), all node features bf16, acc fp32.
// Block: 256 thr = 4 waves in 2x2; BM=64 rows, BN=128 cols. Wave: 32 rows x 64 cols.
__global__ __launch_bounds__(256) void sage_gemm(const __hip_bfloat16* __restrict__ aggb,
                                                 const __hip_bfloat16* __restrict__ hinb,
                                                 const __hip_bfloat16* __restrict__ Wf,
                                                 const float* __restrict__ bias,
                                                 __hip_bfloat16* __restrict__ hout, int n) {
    __shared__ bf16x8 sW[64 * 64];   // 64 KB: [frag][lane]

    const int tid = threadIdx.x;
    #pragma unroll
    for (int it = 0; it < 16; ++it) {
        int idx = tid + it * 256;
        sW[idx] = ((const bf16x8*)Wf)[idx];
    }
    __syncthreads();

    const int w    = tid >> 6;
    const int lane = tid & 63;
    const int wr   = w >> 1, wc = w & 1;
    const int q    = lane >> 4, r = lane & 15;
    const int m0   = blockIdx.x * 64 + wr * 32;

    // A-fragment row indices for the 2 strips (clamped for tail block)
    int rowA0 = m0 + r;        if (rowA0 >= n) rowA0 = 0;
    int rowA1 = m0 + 16 + r;   if (rowA1 >= n) rowA1 = 0;
    const long a0 = (long)rowA0 * 128 + q * 8;   // element offset within feature row
    const long a1 = (long)rowA1 * 128 + q * 8;

    f32x4 acc[2][4];
    #pragma unroll
    for (int s = 0; s < 2; ++s)
        #pragma unroll
        for (int t = 0; t < 4; ++t) acc[s][t] = (f32x4){0.f, 0.f, 0.f, 0.f};

    #pragma unroll
    for (int kstep = 0; kstep < 8; ++kstep) {
        const __hip_bfloat16* base = (kstep < 4) ? aggb : hinb;
        const int ko = (kstep & 3) * 32;
        bf16x8 af0 = *(const bf16x8*)(base + a0 + ko);
        bf16x8 af1 = *(const bf16x8*)(base + a1 + ko);
        #pragma unroll
        for (int t = 0; t < 4; ++t) {
            bf16x8 bf = sW[(kstep * 8 + wc * 4 + t) * 64 + lane];
            acc[0][t] = __builtin_amdgcn_mfma_f32_16x16x32_bf16(af0, bf, acc[0][t], 0, 0, 0);
            acc[1][t] = __builtin_amdgcn_mfma_f32_16x16x32_bf16(af1, bf, acc[1][t], 0, 0, 0);
        }
    }

    #pragma unroll
    for (int t = 0; t < 4; ++t) {
        int col = wc * 64 + t * 16 + r;
        float bv = bias[col];
        #pragma unroll
        for (int s = 0; s < 2; ++s) {
            #pragma unroll
            for (int j = 0; j < 4; ++j) {
                int rowD = m0 + s * 16 + q * 4 + j;
                if (rowD < n) {
                    float v = fmaxf(acc[s][t][j] + bv, 0.f);
                    hout[(long)rowD * F + col] = __float2bfloat16(v);
                }
            }
        }
    }
}

// ---------------------------------------------------------------- pooling (batch sorted, bf16 in)
__global__ __launch_bounds__(128) void pool_kernel(const __hip_bfloat16* __restrict__ h,
                                                   const int* __restrict__ batch,
                                                   float* __restrict__ add_p,
                                                   unsigned* __restrict__ max_p,
                                                   float* __restrict__ cnt, int n) {
    int start = blockIdx.x * 128;
    if (start >= n) return;
    int end = min(start + 128, n);
    int c = threadIdx.x;

    float s = 0.f, mx = 0.f, ct = 0.f;
    int g = batch[start];
    for (int m = start; m < end; ++m) {
        int gm = batch[m];
        if (gm != g) {
            atomicAdd(&add_p[g * F + c], s);
            atomicMax(&max_p[g * F + c], __float_as_uint(mx));
            if (c == 0) atomicAdd(&cnt[g], ct);
            s = 0.f; mx = 0.f; ct = 0.f; g = gm;
        }
        float v = __bfloat162float(h[(long)m * F + c]);
        s += v;
        mx = fmaxf(mx, v);
        ct += 1.f;
    }
    atomicAdd(&add_p[g * F + c], s);
    atomicMax(&max_p[g * F + c], __float_as_uint(mx));
    if (c == 0) atomicAdd(&cnt[g], ct);
}

// ---------------------------------------------------------------- head MLP + log_softmax
__global__ __launch_bounds__(128) void head_kernel(const float* __restrict__ add_p,
                                                   const float* __restrict__ cnt,
                                                   const unsigned* __restrict__ max_p,
                                                   const float* __restrict__ W1,
                                                   const float* __restrict__ b1,
                                                   const float* __restrict__ W2,
                                                   const float* __restrict__ b2,
                                                   float* __restrict__ out) {
    int g = blockIdx.x, n = threadIdx.x;
    __shared__ float gv[384];
    float a    = add_p[g * F + n];
    float invc = 1.f / fmaxf(cnt[g], 1.f);
    gv[n]       = a;
    gv[128 + n] = a * invc;
    gv[256 + n] = __uint_as_float(max_p[g * F + n]);
    __syncthreads();

    float acc = b1[n];
    #pragma unroll 8
    for (int k = 0; k < 384; ++k) acc += gv[k] * W1[k * F + n];
    float r = fmaxf(acc, 0.f);

    float l0 = r * W2[n * 2 + 0];
    float l1 = r * W2[n * 2 + 1];
    #pragma unroll
    for (int off = 32; off > 0; off >>= 1) {
        l0 += __shfl_down(l0, off);
        l1 += __shfl_down(l1, off);
    }
    __shared__ float part[4];
    if ((n & 63) == 0) { part[(n >> 6) * 2] = l0; part[(n >> 6) * 2 + 1] = l1; }
    __syncthreads();
    if (n == 0) {
        float L0 = part[0] + part[2] + b2[0];
        float L1 = part[1] + part[3] + b2[1];
        float m  = fmaxf(L0, L1);
        float lse = m + logf(expf(L0 - m) + expf(L1 - m));
        out[g * 2 + 0] = L0 - lse;
        out[g * 2 + 1] = L1 - lse;
    }
}

// ---------------------------------------------------------------- launch
extern "C" void kernel_launch(void* const* d_in, const int* in_sizes, int n_in,
                              void* d_out, int out_size, void* d_ws, size_t ws_size,
                              hipStream_t stream) {
    const float* x     = (const float*)d_in[0];
    const int*   ei    = (const int*)d_in[1];
    const int*   batch = (const int*)d_in[2];
    const float* Wl0 = (const float*)d_in[3];
    const float* Wr0 = (const float*)d_in[4];
    const float* b0  = (const float*)d_in[5];
    const float* Wl1 = (const float*)d_in[6];
    const float* Wr1 = (const float*)d_in[7];
    const float* b1  = (const float*)d_in[8];
    const float* Wl2 = (const float*)d_in[9];
    const float* Wr2 = (const float*)d_in[10];
    const float* b2  = (const float*)d_in[11];
    const float* W_lin1 = (const float*)d_in[12];
    const float* b_lin1 = (const float*)d_in[13];
    const float* W_lin2 = (const float*)d_in[14];
    const float* b_lin2 = (const float*)d_in[15];

    const int nE = in_sizes[1] / 2;
    const int* src = ei;
    const int* dst = ei + nE;

    // workspace layout (16B-aligned chunks)
    char* p = (char*)d_ws;
    int*   deg     = (int*)p;            p += 50048 * 4;
    int*   row_ptr = (int*)p;            p += 50048 * 4;
    int*   cursor  = (int*)p;            p += 50048 * 4;
    int*   bsum    = (int*)p;            p += 256 * 4;
    int*   boff    = (int*)p;            p += 256 * 4;
    int*   csr_src = (int*)p;            p += (long)nE * 4;
    __hip_bfloat16* xb   = (__hip_bfloat16*)p; p += (long)N_NODES * F * 2;
    __hip_bfloat16* aggb = (__hip_bfloat16*)p; p += (long)N_NODES * F * 2;
    __hip_bfloat16* h1b  = (__hip_bfloat16*)p; p += (long)N_NODES * F * 2;
    __hip_bfloat16* h2b  = (__hip_bfloat16*)p; p += (long)N_NODES * F * 2;
    __hip_bfloat16* h3b  = (__hip_bfloat16*)p; p += (long)N_NODES * F * 2;
    __hip_bfloat16* Wf0  = (__hip_bfloat16*)p; p += 32768 * 2;
    __hip_bfloat16* Wf1  = (__hip_bfloat16*)p; p += 32768 * 2;
    __hip_bfloat16* Wf2  = (__hip_bfloat16*)p; p += 32768 * 2;
    float* add_p   = (float*)p;          p += NGRAPH * F * 4;
    unsigned* max_p = (unsigned*)p;      p += NGRAPH * F * 4;
    float* cnt     = (float*)p;          p += 256;

    const int gridE = (nE + 255) / 256;
    const int gridG = (N_NODES + 63) / 64;
    const int gridW = (N_NODES + 3) / 4;
    const int gridP = (N_NODES + 127) / 128;
    const int gridC = (int)(((long)N_NODES * F / 4 + 255) / 256);

    // ---- CSR build
    hipMemsetAsync(deg, 0, N_NODES * sizeof(int), stream);
    deg_kernel<<<gridE, 256, 0, stream>>>(dst, deg, nE);
    scan_part<<<NCHUNK, 256, 0, stream>>>(deg, bsum, N_NODES);
    scan_block<<<1, 256, 0, stream>>>(bsum, boff);
    scan_final<<<NCHUNK, 256, 0, stream>>>(deg, boff, row_ptr, cursor, N_NODES);
    place_kernel<<<gridE, 256, 0, stream>>>(src, dst, cursor, csr_src, nE);

    // ---- precompute bf16 inputs + fragment-packed weights
    cvt_kernel<<<gridC, 256, 0, stream>>>(x, xb, (long)N_NODES * F / 4);
    wfrag_kernel<<<16, 256, 0, stream>>>(Wl0, Wr0, Wf0);
    wfrag_kernel<<<16, 256, 0, stream>>>(Wl1, Wr1, Wf1);
    wfrag_kernel<<<16, 256, 0, stream>>>(Wl2, Wr2, Wf2);

    // ---- layer 0
    gather_kernel<<<gridW, 256, 0, stream>>>(xb, row_ptr, csr_src, aggb, N_NODES);
    sage_gemm<<<gridG, 256, 0, stream>>>(aggb, xb, Wf0, b0, h1b, N_NODES);
    // ---- layer 1
    gather_kernel<<<gridW, 256, 0, stream>>>(h1b, row_ptr, csr_src, aggb, N_NODES);
    sage_gemm<<<gridG, 256, 0, stream>>>(aggb, h1b, Wf1, b1, h2b, N_NODES);
    // ---- layer 2
    gather_kernel<<<gridW, 256, 0, stream>>>(h2b, row_ptr, csr_src, aggb, N_NODES);
    sage_gemm<<<gridG, 256, 0, stream>>>(aggb, h2b, Wf2, b2, h3b, N_NODES);

    // ---- pooling
    hipMemsetAsync(add_p, 0, (NGRAPH * F * 2 + NGRAPH) * sizeof(float), stream);
    pool_kernel<<<gridP, 128, 0, stream>>>(h3b, batch, add_p, max_p, cnt, N_NODES);

    // ---- head
    head_kernel<<<NGRAPH, 128, 0, stream>>>(add_p, cnt, max_p,
                                            W_lin1, b_lin1, W_lin2, b_lin2,
                                            (float*)d_out);
}

// Round 4
// 351.669 us; speedup vs baseline: 23.9638x; 1.4232x over previous
//
#include <hip/hip_runtime.h>
#include <hip/hip_bf16.h>

#define N_NODES   50000
#define F         128
#define NGRAPH    64
#define NB        391     // number of dst buckets: (50000+127)/128
#define B1        400     // edge-chunk blocks for multisplit

typedef __attribute__((ext_vector_type(8))) short  bf16x8;
typedef __attribute__((ext_vector_type(4))) float  f32x4;

// ================================================================ CSR build (atomic-free multisplit)
// Pass A: per-block LDS histogram over NB buckets (bucket = dst>>7)
__global__ __launch_bounds__(256) void bucket_hist(const int* __restrict__ dst,
                                                   int* __restrict__ bh, int nE, int chunk) {
    __shared__ int hist[NB];
    for (int i = threadIdx.x; i < NB; i += 256) hist[i] = 0;
    __syncthreads();
    int e0 = blockIdx.x * chunk;
    int e1 = min(e0 + chunk, nE);
    for (int e = e0 + threadIdx.x; e < e1; e += 256)
        atomicAdd(&hist[dst[e] >> 7], 1);
    __syncthreads();
    for (int i = threadIdx.x; i < NB; i += 256)
        bh[i * B1 + blockIdx.x] = hist[i];
}

// Pass B1: exclusive scan over blocks within each bucket
__global__ __launch_bounds__(512) void scan_blocks(const int* __restrict__ bh,
                                                   int* __restrict__ boff,
                                                   int* __restrict__ btot) {
    __shared__ int s[512];
    int bkt = blockIdx.x, t = threadIdx.x;
    int v = (t < B1) ? bh[bkt * B1 + t] : 0;
    s[t] = v;
    __syncthreads();
    for (int off = 1; off < 512; off <<= 1) {
        int u = (t >= off) ? s[t - off] : 0;
        __syncthreads();
        s[t] += u;
        __syncthreads();
    }
    if (t < B1) boff[bkt * B1 + t] = s[t] - v;
    if (t == B1 - 1) btot[bkt] = s[t];
}

// Pass B2: exclusive scan over bucket totals -> bucket edge bases
__global__ __launch_bounds__(512) void scan_buckets(const int* __restrict__ btot,
                                                    int* __restrict__ bbase) {
    __shared__ int s[512];
    int t = threadIdx.x;
    int v = (t < NB) ? btot[t] : 0;
    s[t] = v;
    __syncthreads();
    for (int off = 1; off < 512; off <<= 1) {
        int u = (t >= off) ? s[t - off] : 0;
        __syncthreads();
        s[t] += u;
        __syncthreads();
    }
    if (t < NB) bbase[t] = s[t] - v;
    if (t == NB - 1) bbase[NB] = s[t];
}

// Pass C: place edges into bucket-sorted ebuf via LDS cursors (no global atomics)
__global__ __launch_bounds__(256) void bucket_place(const int* __restrict__ src,
                                                    const int* __restrict__ dst,
                                                    const int* __restrict__ boff,
                                                    const int* __restrict__ bbase,
                                                    int2* __restrict__ ebuf, int nE, int chunk) {
    __shared__ int cur[NB];
    for (int i = threadIdx.x; i < NB; i += 256)
        cur[i] = bbase[i] + boff[i * B1 + blockIdx.x];
    __syncthreads();
    int e0 = blockIdx.x * chunk;
    int e1 = min(e0 + chunk, nE);
    for (int e = e0 + threadIdx.x; e < e1; e += 256) {
        int d = dst[e];
        int pos = atomicAdd(&cur[d >> 7], 1);   // LDS atomic
        ebuf[pos] = make_int2(src[e], d);
    }
}

// Pass D: per-bucket CSR finalize — row_ptr + csr_src, writes contiguous per bucket
__global__ __launch_bounds__(256) void csr_build(const int2* __restrict__ ebuf,
                                                 const int* __restrict__ bbase,
                                                 int* __restrict__ row_ptr,
                                                 int* __restrict__ csr_src, int n) {
    __shared__ int hist[128];
    __shared__ int cursor[128];
    int b = blockIdx.x, t = threadIdx.x;
    int e0 = bbase[b], e1 = bbase[b + 1];
    if (t < 128) hist[t] = 0;
    __syncthreads();
    for (int e = e0 + t; e < e1; e += 256)
        atomicAdd(&hist[ebuf[e].y & 127], 1);   // LDS atomic
    __syncthreads();
    if (t == 0) {
        int run = e0;
        #pragma unroll 4
        for (int i = 0; i < 128; ++i) { cursor[i] = run; run += hist[i]; }
    }
    __syncthreads();
    int node = b * 128 + t;
    if (t < 128 && node < n) row_ptr[node] = cursor[t];
    if (b == NB - 1 && t == 0) row_ptr[n] = e1;
    __syncthreads();
    for (int e = e0 + t; e < e1; e += 256) {
        int2 ed = ebuf[e];
        int pos = atomicAdd(&cursor[ed.y & 127], 1);   // LDS atomic
        csr_src[pos] = ed.x;
    }
}

// ================================================================ fp32 -> bf16 convert
struct bh4 { __hip_bfloat16 a, b, c, d; };
__global__ __launch_bounds__(256) void cvt_kernel(const float* __restrict__ in,
                                                  __hip_bfloat16* __restrict__ out, long n4) {
    long i = (long)blockIdx.x * 256 + threadIdx.x;
    if (i >= n4) return;
    float4 v = ((const float4*)in)[i];
    bh4 o;
    o.a = __float2bfloat16(v.x);
    o.b = __float2bfloat16(v.y);
    o.c = __float2bfloat16(v.z);
    o.d = __float2bfloat16(v.w);
    ((bh4*)out)[i] = o;
}

// ================================================================ gather-mean (bf16 in/out)
__global__ __launch_bounds__(256) void gather_kernel(const __hip_bfloat16* __restrict__ xin,
                                                     const int* __restrict__ row_ptr,
                                                     const int* __restrict__ csr_src,
                                                     __hip_bfloat16* __restrict__ agg, int n) {
    int node = blockIdx.x * 4 + (threadIdx.x >> 6);
    if (node >= n) return;
    int lane = threadIdx.x & 63;

    const unsigned* __restrict__ xr = (const unsigned*)xin;
    int beg = row_ptr[node], end = row_ptr[node + 1];

    float ax0 = 0.f, ay0 = 0.f, ax1 = 0.f, ay1 = 0.f;
    float ax2 = 0.f, ay2 = 0.f, ax3 = 0.f, ay3 = 0.f;
    int i = beg;
    for (; i + 3 < end; i += 4) {
        unsigned v0 = xr[(long)csr_src[i + 0] * 64 + lane];
        unsigned v1 = xr[(long)csr_src[i + 1] * 64 + lane];
        unsigned v2 = xr[(long)csr_src[i + 2] * 64 + lane];
        unsigned v3 = xr[(long)csr_src[i + 3] * 64 + lane];
        ax0 += __uint_as_float(v0 << 16); ay0 += __uint_as_float(v0 & 0xffff0000u);
        ax1 += __uint_as_float(v1 << 16); ay1 += __uint_as_float(v1 & 0xffff0000u);
        ax2 += __uint_as_float(v2 << 16); ay2 += __uint_as_float(v2 & 0xffff0000u);
        ax3 += __uint_as_float(v3 << 16); ay3 += __uint_as_float(v3 & 0xffff0000u);
    }
    for (; i < end; ++i) {
        unsigned v0 = xr[(long)csr_src[i] * 64 + lane];
        ax0 += __uint_as_float(v0 << 16); ay0 += __uint_as_float(v0 & 0xffff0000u);
    }
    float inv = 1.f / fmaxf((float)(end - beg), 1.f);
    float sx = (ax0 + ax1 + ax2 + ax3) * inv;
    float sy = (ay0 + ay1 + ay2 + ay3) * inv;
    __hip_bfloat162 o;
    o.x = __float2bfloat16(sx);
    o.y = __float2bfloat16(sy);
    ((__hip_bfloat162*)agg)[(long)node * 64 + lane] = o;
}

// ================================================================ W fragment pre-pack
__global__ __launch_bounds__(256) void wfrag_kernel(const float* __restrict__ Wl,
                                                    const float* __restrict__ Wr,
                                                    __hip_bfloat16* __restrict__ Wf) {
    int t = blockIdx.x * 256 + threadIdx.x;   // 4096 threads
    int frag = t >> 6, lane = t & 63;
    int kstep = frag >> 3, ntg = frag & 7;
    int q = lane >> 4, r = lane & 15;
    short vals[8];
    #pragma unroll
    for (int j = 0; j < 8; ++j) {
        int krow = kstep * 32 + q * 8 + j;
        int col  = ntg * 16 + r;
        float f  = (krow < 128) ? Wl[krow * F + col] : Wr[(krow - 128) * F + col];
        __hip_bfloat16 h = __float2bfloat16(f);
        vals[j] = *(short*)&h;
    }
    bf16x8 v;
    #pragma unroll
    for (int j = 0; j < 8; ++j) v[j] = vals[j];
    ((bf16x8*)Wf)[t] = v;
}

// ================================================================ MFMA SAGE GEMM
__global__ __launch_bounds__(256) void sage_gemm(const __hip_bfloat16* __restrict__ aggb,
                                                 const __hip_bfloat16* __restrict__ hinb,
                                                 const __hip_bfloat16* __restrict__ Wf,
                                                 const float* __restrict__ bias,
                                                 __hip_bfloat16* __restrict__ hout, int n) {
    __shared__ bf16x8 sW[64 * 64];

    const int tid = threadIdx.x;
    #pragma unroll
    for (int it = 0; it < 16; ++it) {
        int idx = tid + it * 256;
        sW[idx] = ((const bf16x8*)Wf)[idx];
    }
    __syncthreads();

    const int w    = tid >> 6;
    const int lane = tid & 63;
    const int wr   = w >> 1, wc = w & 1;
    const int q    = lane >> 4, r = lane & 15;
    const int m0   = blockIdx.x * 64 + wr * 32;

    int rowA0 = m0 + r;        if (rowA0 >= n) rowA0 = 0;
    int rowA1 = m0 + 16 + r;   if (rowA1 >= n) rowA1 = 0;
    const long a0 = (long)rowA0 * 128 + q * 8;
    const long a1 = (long)rowA1 * 128 + q * 8;

    f32x4 acc[2][4];
    #pragma unroll
    for (int s = 0; s < 2; ++s)
        #pragma unroll
        for (int t = 0; t < 4; ++t) acc[s][t] = (f32x4){0.f, 0.f, 0.f, 0.f};

    #pragma unroll
    for (int kstep = 0; kstep < 8; ++kstep) {
        const __hip_bfloat16* base = (kstep < 4) ? aggb : hinb;
        const int ko = (kstep & 3) * 32;
        bf16x8 af0 = *(const bf16x8*)(base + a0 + ko);
        bf16x8 af1 = *(const bf16x8*)(base + a1 + ko);
        #pragma unroll
        for (int t = 0; t < 4; ++t) {
            bf16x8 bf = sW[(kstep * 8 + wc * 4 + t) * 64 + lane];
            acc[0][t] = __builtin_amdgcn_mfma_f32_16x16x32_bf16(af0, bf, acc[0][t], 0, 0, 0);
            acc[1][t] = __builtin_amdgcn_mfma_f32_16x16x32_bf16(af1, bf, acc[1][t], 0, 0, 0);
        }
    }

    #pragma unroll
    for (int t = 0; t < 4; ++t) {
        int col = wc * 64 + t * 16 + r;
        float bv = bias[col];
        #pragma unroll
        for (int s = 0; s < 2; ++s) {
            #pragma unroll
            for (int j = 0; j < 4; ++j) {
                int rowD = m0 + s * 16 + q * 4 + j;
                if (rowD < n) {
                    float v = fmaxf(acc[s][t][j] + bv, 0.f);
                    hout[(long)rowD * F + col] = __float2bfloat16(v);
                }
            }
        }
    }
}

// ================================================================ pooling (batch sorted)
__global__ __launch_bounds__(128) void pool_kernel(const __hip_bfloat16* __restrict__ h,
                                                   const int* __restrict__ batch,
                                                   float* __restrict__ add_p,
                                                   unsigned* __restrict__ max_p,
                                                   float* __restrict__ cnt, int n) {
    int start = blockIdx.x * 128;
    if (start >= n) return;
    int end = min(start + 128, n);
    int c = threadIdx.x;

    float s = 0.f, mx = 0.f, ct = 0.f;
    int g = batch[start];
    for (int m = start; m < end; ++m) {
        int gm = batch[m];
        if (gm != g) {
            atomicAdd(&add_p[g * F + c], s);
            atomicMax(&max_p[g * F + c], __float_as_uint(mx));
            if (c == 0) atomicAdd(&cnt[g], ct);
            s = 0.f; mx = 0.f; ct = 0.f; g = gm;
        }
        float v = __bfloat162float(h[(long)m * F + c]);
        s += v;
        mx = fmaxf(mx, v);
        ct += 1.f;
    }
    atomicAdd(&add_p[g * F + c], s);
    atomicMax(&max_p[g * F + c], __float_as_uint(mx));
    if (c == 0) atomicAdd(&cnt[g], ct);
}

// ================================================================ head MLP + log_softmax
__global__ __launch_bounds__(128) void head_kernel(const float* __restrict__ add_p,
                                                   const float* __restrict__ cnt,
                                                   const unsigned* __restrict__ max_p,
                                                   const float* __restrict__ W1,
                                                   const float* __restrict__ b1,
                                                   const float* __restrict__ W2,
                                                   const float* __restrict__ b2,
                                                   float* __restrict__ out) {
    int g = blockIdx.x, n = threadIdx.x;
    __shared__ float gv[384];
    float a    = add_p[g * F + n];
    float invc = 1.f / fmaxf(cnt[g], 1.f);
    gv[n]       = a;
    gv[128 + n] = a * invc;
    gv[256 + n] = __uint_as_float(max_p[g * F + n]);
    __syncthreads();

    float acc = b1[n];
    #pragma unroll 8
    for (int k = 0; k < 384; ++k) acc += gv[k] * W1[k * F + n];
    float r = fmaxf(acc, 0.f);

    float l0 = r * W2[n * 2 + 0];
    float l1 = r * W2[n * 2 + 1];
    #pragma unroll
    for (int off = 32; off > 0; off >>= 1) {
        l0 += __shfl_down(l0, off);
        l1 += __shfl_down(l1, off);
    }
    __shared__ float part[4];
    if ((n & 63) == 0) { part[(n >> 6) * 2] = l0; part[(n >> 6) * 2 + 1] = l1; }
    __syncthreads();
    if (n == 0) {
        float L0 = part[0] + part[2] + b2[0];
        float L1 = part[1] + part[3] + b2[1];
        float m  = fmaxf(L0, L1);
        float lse = m + logf(expf(L0 - m) + expf(L1 - m));
        out[g * 2 + 0] = L0 - lse;
        out[g * 2 + 1] = L1 - lse;
    }
}

// ================================================================ launch
extern "C" void kernel_launch(void* const* d_in, const int* in_sizes, int n_in,
                              void* d_out, int out_size, void* d_ws, size_t ws_size,
                              hipStream_t stream) {
    const float* x     = (const float*)d_in[0];
    const int*   ei    = (const int*)d_in[1];
    const int*   batch = (const int*)d_in[2];
    const float* Wl0 = (const float*)d_in[3];
    const float* Wr0 = (const float*)d_in[4];
    const float* b0  = (const float*)d_in[5];
    const float* Wl1 = (const float*)d_in[6];
    const float* Wr1 = (const float*)d_in[7];
    const float* b1  = (const float*)d_in[8];
    const float* Wl2 = (const float*)d_in[9];
    const float* Wr2 = (const float*)d_in[10];
    const float* b2  = (const float*)d_in[11];
    const float* W_lin1 = (const float*)d_in[12];
    const float* b_lin1 = (const float*)d_in[13];
    const float* W_lin2 = (const float*)d_in[14];
    const float* b_lin2 = (const float*)d_in[15];

    const int nE = in_sizes[1] / 2;
    const int* src = ei;
    const int* dst = ei + nE;

    // workspace layout (16B-aligned chunks)
    char* p = (char*)d_ws;
    int*   row_ptr = (int*)p;            p += 50048 * 4;
    int*   csr_src = (int*)p;            p += (((long)nE + 3) & ~3L) * 4;
    int*   bh      = (int*)p;            p += (long)NB * B1 * 4 + 64;
    int*   boff    = (int*)p;            p += (long)NB * B1 * 4 + 64;
    int*   btot    = (int*)p;            p += 512 * 4;
    int*   bbase   = (int*)p;            p += 512 * 4;
    __hip_bfloat16* xb   = (__hip_bfloat16*)p; p += (long)N_NODES * F * 2;
    __hip_bfloat16* aggb = (__hip_bfloat16*)p; p += (long)N_NODES * F * 2;
    __hip_bfloat16* h1b  = (__hip_bfloat16*)p; p += (long)N_NODES * F * 2;
    __hip_bfloat16* h2b  = (__hip_bfloat16*)p; p += (long)N_NODES * F * 2;
    __hip_bfloat16* h3b  = (__hip_bfloat16*)p; p += (long)N_NODES * F * 2;
    __hip_bfloat16* Wf0  = (__hip_bfloat16*)p; p += 32768 * 2;
    __hip_bfloat16* Wf1  = (__hip_bfloat16*)p; p += 32768 * 2;
    __hip_bfloat16* Wf2  = (__hip_bfloat16*)p; p += 32768 * 2;
    float* add_p   = (float*)p;          p += NGRAPH * F * 4;
    unsigned* max_p = (unsigned*)p;      p += NGRAPH * F * 4;
    float* cnt     = (float*)p;          p += 256;

    // ebuf (12.8 MB) aliases aggb: dead once csr_build finishes, before first gather writes aggb
    int2* ebuf = (int2*)aggb;

    const int chunk = (nE + B1 - 1) / B1;
    const int gridG = (N_NODES + 63) / 64;
    const int gridW = (N_NODES + 3) / 4;
    const int gridP = (N_NODES + 127) / 128;
    const int gridC = (int)(((long)N_NODES * F / 4 + 255) / 256);

    // ---- CSR build: deterministic multisplit, no global atomics
    bucket_hist <<<B1, 256, 0, stream>>>(dst, bh, nE, chunk);
    scan_blocks <<<NB, 512, 0, stream>>>(bh, boff, btot);
    scan_buckets<<<1,  512, 0, stream>>>(btot, bbase);
    bucket_place<<<B1, 256, 0, stream>>>(src, dst, boff, bbase, ebuf, nE, chunk);
    csr_build   <<<NB, 256, 0, stream>>>(ebuf, bbase, row_ptr, csr_src, N_NODES);

    // ---- bf16 inputs + fragment-packed weights
    cvt_kernel<<<gridC, 256, 0, stream>>>(x, xb, (long)N_NODES * F / 4);
    wfrag_kernel<<<16, 256, 0, stream>>>(Wl0, Wr0, Wf0);
    wfrag_kernel<<<16, 256, 0, stream>>>(Wl1, Wr1, Wf1);
    wfrag_kernel<<<16, 256, 0, stream>>>(Wl2, Wr2, Wf2);

    // ---- layer 0
    gather_kernel<<<gridW, 256, 0, stream>>>(xb, row_ptr, csr_src, aggb, N_NODES);
    sage_gemm<<<gridG, 256, 0, stream>>>(aggb, xb, Wf0, b0, h1b, N_NODES);
    // ---- layer 1
    gather_kernel<<<gridW, 256, 0, stream>>>(h1b, row_ptr, csr_src, aggb, N_NODES);
    sage_gemm<<<gridG, 256, 0, stream>>>(aggb, h1b, Wf1, b1, h2b, N_NODES);
    // ---- layer 2
    gather_kernel<<<gridW, 256, 0, stream>>>(h2b, row_ptr, csr_src, aggb, N_NODES);
    sage_gemm<<<gridG, 256, 0, stream>>>(aggb, h2b, Wf2, b2, h3b, N_NODES);

    // ---- pooling
    hipMemsetAsync(add_p, 0, (NGRAPH * F * 2 + NGRAPH) * sizeof(float), stream);
    pool_kernel<<<gridP, 128, 0, stream>>>(h3b, batch, add_p, max_p, cnt, N_NODES);

    // ---- head
    head_kernel<<<NGRAPH, 128, 0, stream>>>(add_p, cnt, max_p,
                                            W_lin1, b_lin1, W_lin2, b_lin2,
                                            (float*)d_out);
}

// Round 5
// 315.380 us; speedup vs baseline: 26.7212x; 1.1151x over previous
//
#include <hip/hip_runtime.h>
#include <hip/hip_bf16.h>

#define N_NODES   50000
#define ZROW      N_NODES        // sentinel zero-row index
#define F         128
#define NGRAPH    64
#define NB        391            // dst buckets: (50000+127)/128
#define B1        400            // edge-chunk blocks for multisplit
#define PADMAX    384            // max pad per bucket (128 nodes * 3)

typedef __attribute__((ext_vector_type(8))) short  bf16x8;
typedef __attribute__((ext_vector_type(4))) float  f32x4;

// ================================================================ CSR build (atomic-free multisplit)
__global__ __launch_bounds__(256) void bucket_hist(const int* __restrict__ dst,
                                                   int* __restrict__ bh, int nE, int chunk) {
    __shared__ int hist[NB];
    for (int i = threadIdx.x; i < NB; i += 256) hist[i] = 0;
    __syncthreads();
    int e0 = blockIdx.x * chunk;
    int e1 = min(e0 + chunk, nE);
    for (int e = e0 + threadIdx.x; e < e1; e += 256)
        atomicAdd(&hist[dst[e] >> 7], 1);
    __syncthreads();
    for (int i = threadIdx.x; i < NB; i += 256)
        bh[i * B1 + blockIdx.x] = hist[i];
}

__global__ __launch_bounds__(512) void scan_blocks(const int* __restrict__ bh,
                                                   int* __restrict__ boff,
                                                   int* __restrict__ btot) {
    __shared__ int s[512];
    int bkt = blockIdx.x, t = threadIdx.x;
    int v = (t < B1) ? bh[bkt * B1 + t] : 0;
    s[t] = v;
    __syncthreads();
    for (int off = 1; off < 512; off <<= 1) {
        int u = (t >= off) ? s[t - off] : 0;
        __syncthreads();
        s[t] += u;
        __syncthreads();
    }
    if (t < B1) boff[bkt * B1 + t] = s[t] - v;
    if (t == B1 - 1) btot[bkt] = s[t];
}

__global__ __launch_bounds__(512) void scan_buckets(const int* __restrict__ btot,
                                                    int* __restrict__ bbase) {
    __shared__ int s[512];
    int t = threadIdx.x;
    int v = (t < NB) ? btot[t] : 0;
    s[t] = v;
    __syncthreads();
    for (int off = 1; off < 512; off <<= 1) {
        int u = (t >= off) ? s[t - off] : 0;
        __syncthreads();
        s[t] += u;
        __syncthreads();
    }
    if (t < NB) bbase[t] = s[t] - v;
    if (t == NB - 1) bbase[NB] = s[t];
}

// Pass C: place edges into bucket-sorted ebuf (ushort2) via LDS cursors
__global__ __launch_bounds__(256) void bucket_place(const int* __restrict__ src,
                                                    const int* __restrict__ dst,
                                                    const int* __restrict__ boff,
                                                    const int* __restrict__ bbase,
                                                    ushort2* __restrict__ ebuf, int nE, int chunk) {
    __shared__ int cur[NB];
    for (int i = threadIdx.x; i < NB; i += 256)
        cur[i] = bbase[i] + boff[i * B1 + blockIdx.x];
    __syncthreads();
    int e0 = blockIdx.x * chunk;
    int e1 = min(e0 + chunk, nE);
    for (int e = e0 + threadIdx.x; e < e1; e += 256) {
        int d = dst[e];
        int pos = atomicAdd(&cur[d >> 7], 1);   // LDS atomic
        ebuf[pos] = make_ushort2((unsigned short)src[e], (unsigned short)(d & 127));
    }
}

// Pass D: per-bucket CSR finalize — padded row_ptr, real deg, ushort csr, sentinel pads
__global__ __launch_bounds__(256) void csr_build(const ushort2* __restrict__ ebuf,
                                                 const int* __restrict__ bbase,
                                                 int* __restrict__ row_ptr,
                                                 int* __restrict__ deg_arr,
                                                 unsigned short* __restrict__ csr, int n) {
    __shared__ int hist[128];
    __shared__ int cursor[128];
    __shared__ int pend[128];
    int b = blockIdx.x, t = threadIdx.x;
    int e0 = bbase[b], e1 = bbase[b + 1];
    if (t < 128) hist[t] = 0;
    __syncthreads();
    for (int e = e0 + t; e < e1; e += 256)
        atomicAdd(&hist[ebuf[e].y], 1);          // LDS atomic
    __syncthreads();
    if (t == 0) {
        int run = e0 + b * PADMAX;
        #pragma unroll 4
        for (int i = 0; i < 128; ++i) { cursor[i] = run; run += (hist[i] + 3) & ~3; }
    }
    __syncthreads();
    int node = b * 128 + t;
    if (t < 128) {
        pend[t] = cursor[t] + ((hist[t] + 3) & ~3);
        if (node < n) { row_ptr[node] = cursor[t]; deg_arr[node] = hist[t]; }
    }
    __syncthreads();
    for (int e = e0 + t; e < e1; e += 256) {
        ushort2 ed = ebuf[e];
        int pos = atomicAdd(&cursor[ed.y], 1);   // LDS atomic
        csr[pos] = ed.x;
    }
    __syncthreads();
    if (t < 128)
        for (int p = cursor[t]; p < pend[t]; ++p) csr[p] = (unsigned short)ZROW;
}

// ================================================================ fp32 -> bf16 convert
struct bh4 { __hip_bfloat16 a, b, c, d; };
__global__ __launch_bounds__(256) void cvt_kernel(const float* __restrict__ in,
                                                  __hip_bfloat16* __restrict__ out, long n4) {
    long i = (long)blockIdx.x * 256 + threadIdx.x;
    if (i >= n4) return;
    float4 v = ((const float4*)in)[i];
    bh4 o;
    o.a = __float2bfloat16(v.x);
    o.b = __float2bfloat16(v.y);
    o.c = __float2bfloat16(v.z);
    o.d = __float2bfloat16(v.w);
    ((bh4*)out)[i] = o;
}

// zero the sentinel rows of the three gather-input tables
__global__ __launch_bounds__(64) void zero_rows(__hip_bfloat16* __restrict__ xb,
                                                __hip_bfloat16* __restrict__ h1,
                                                __hip_bfloat16* __restrict__ h2) {
    int t = threadIdx.x;
    if (t < 48) {
        __hip_bfloat16* base = (t < 16) ? xb : (t < 32) ? h1 : h2;
        ((uint4*)(base + (long)ZROW * F))[t & 15] = make_uint4(0, 0, 0, 0);
    }
}

// ================================================================ gather-mean (wide, padded)
// Wave per node. Quarter q (16 lanes) handles edge i+q; lane slot r (lane&15) owns 16 B
// of the 256-B row. Padded adjacency (multiple of 4, sentinel=zero row) -> no tail.
__global__ __launch_bounds__(256) void gather_kernel(const __hip_bfloat16* __restrict__ xin,
                                                     const int* __restrict__ row_ptr,
                                                     const int* __restrict__ deg_arr,
                                                     const unsigned short* __restrict__ csr,
                                                     __hip_bfloat16* __restrict__ agg, int n) {
    int node = blockIdx.x * 4 + (threadIdx.x >> 6);
    if (node >= n) return;
    const int lane = threadIdx.x & 63;
    const int q = lane >> 4;
    const int r = lane & 15;

    const int beg = row_ptr[node];
    const int d   = deg_arr[node];
    const int end = beg + ((d + 3) & ~3);

    const uint4* __restrict__ xr4 = (const uint4*)xin;   // row = 16 x uint4

    float2 a0 = {0.f, 0.f}, a1 = {0.f, 0.f}, a2 = {0.f, 0.f}, a3 = {0.f, 0.f};

    #pragma unroll 2
    for (int i = beg; i < end; i += 4) {
        int s = (int)csr[i + q];                 // per-lane ushort load (4 addrs/wave)
        uint4 v = xr4[(unsigned)s * 16u + r];    // 16 B of row s
        a0.x += __uint_as_float(v.x << 16); a0.y += __uint_as_float(v.x & 0xffff0000u);
        a1.x += __uint_as_float(v.y << 16); a1.y += __uint_as_float(v.y & 0xffff0000u);
        a2.x += __uint_as_float(v.z << 16); a2.y += __uint_as_float(v.z & 0xffff0000u);
        a3.x += __uint_as_float(v.w << 16); a3.y += __uint_as_float(v.w & 0xffff0000u);
    }

    // reduce across quarters: lanes r, r+16, r+32, r+48 hold partials of the same slot
    float v8[8] = {a0.x, a0.y, a1.x, a1.y, a2.x, a2.y, a3.x, a3.y};
    #pragma unroll
    for (int j = 0; j < 8; ++j) {
        v8[j] += __shfl_xor(v8[j], 16);
        v8[j] += __shfl_xor(v8[j], 32);
    }

    if (q == 0) {
        float inv = 1.f / fmaxf((float)d, 1.f);
        unsigned o[4];
        #pragma unroll
        for (int k = 0; k < 4; ++k) {
            __hip_bfloat16 lo = __float2bfloat16(v8[2 * k]     * inv);
            __hip_bfloat16 hi = __float2bfloat16(v8[2 * k + 1] * inv);
            o[k] = (unsigned)*(unsigned short*)&lo | ((unsigned)*(unsigned short*)&hi << 16);
        }
        ((uint4*)agg)[(long)node * 16 + r] = make_uint4(o[0], o[1], o[2], o[3]);
    }
}

// ================================================================ W fragment pre-pack (all 3 layers)
__global__ __launch_bounds__(256) void wfrag_all(const float* __restrict__ Wl0, const float* __restrict__ Wr0,
                                                 const float* __restrict__ Wl1, const float* __restrict__ Wr1,
                                                 const float* __restrict__ Wl2, const float* __restrict__ Wr2,
                                                 __hip_bfloat16* __restrict__ Wf) {
    int layer = blockIdx.x >> 4;
    int t = (blockIdx.x & 15) * 256 + threadIdx.x;   // 0..4095
    const float* Wl = (layer == 0) ? Wl0 : (layer == 1) ? Wl1 : Wl2;
    const float* Wr = (layer == 0) ? Wr0 : (layer == 1) ? Wr1 : Wr2;
    int frag = t >> 6, lane = t & 63;
    int kstep = frag >> 3, ntg = frag & 7;
    int q = lane >> 4, r = lane & 15;
    bf16x8 v;
    #pragma unroll
    for (int j = 0; j < 8; ++j) {
        int krow = kstep * 32 + q * 8 + j;
        int col  = ntg * 16 + r;
        float f  = (krow < 128) ? Wl[krow * F + col] : Wr[(krow - 128) * F + col];
        __hip_bfloat16 h = __float2bfloat16(f);
        v[j] = *(short*)&h;
    }
    ((bf16x8*)(Wf + (long)layer * 32768))[t] = v;
}

// ================================================================ MFMA SAGE GEMM
__global__ __launch_bounds__(256) void sage_gemm(const __hip_bfloat16* __restrict__ aggb,
                                                 const __hip_bfloat16* __restrict__ hinb,
                                                 const __hip_bfloat16* __restrict__ Wf,
                                                 const float* __restrict__ bias,
                                                 __hip_bfloat16* __restrict__ hout, int n) {
    __shared__ bf16x8 sW[64 * 64];

    const int tid = threadIdx.x;
    #pragma unroll
    for (int it = 0; it < 16; ++it) {
        int idx = tid + it * 256;
        sW[idx] = ((const bf16x8*)Wf)[idx];
    }
    __syncthreads();

    const int w    = tid >> 6;
    const int lane = tid & 63;
    const int wr   = w >> 1, wc = w & 1;
    const int q    = lane >> 4, r = lane & 15;
    const int m0   = blockIdx.x * 64 + wr * 32;

    int rowA0 = m0 + r;        if (rowA0 >= n) rowA0 = 0;
    int rowA1 = m0 + 16 + r;   if (rowA1 >= n) rowA1 = 0;
    const long a0 = (long)rowA0 * 128 + q * 8;
    const long a1 = (long)rowA1 * 128 + q * 8;

    f32x4 acc[2][4];
    #pragma unroll
    for (int s = 0; s < 2; ++s)
        #pragma unroll
        for (int t = 0; t < 4; ++t) acc[s][t] = (f32x4){0.f, 0.f, 0.f, 0.f};

    #pragma unroll
    for (int kstep = 0; kstep < 8; ++kstep) {
        const __hip_bfloat16* base = (kstep < 4) ? aggb : hinb;
        const int ko = (kstep & 3) * 32;
        bf16x8 af0 = *(const bf16x8*)(base + a0 + ko);
        bf16x8 af1 = *(const bf16x8*)(base + a1 + ko);
        #pragma unroll
        for (int t = 0; t < 4; ++t) {
            bf16x8 bf = sW[(kstep * 8 + wc * 4 + t) * 64 + lane];
            acc[0][t] = __builtin_amdgcn_mfma_f32_16x16x32_bf16(af0, bf, acc[0][t], 0, 0, 0);
            acc[1][t] = __builtin_amdgcn_mfma_f32_16x16x32_bf16(af1, bf, acc[1][t], 0, 0, 0);
        }
    }

    #pragma unroll
    for (int t = 0; t < 4; ++t) {
        int col = wc * 64 + t * 16 + r;
        float bv = bias[col];
        #pragma unroll
        for (int s = 0; s < 2; ++s) {
            #pragma unroll
            for (int j = 0; j < 4; ++j) {
                int rowD = m0 + s * 16 + q * 4 + j;
                if (rowD < n) {
                    float v = fmaxf(acc[s][t][j] + bv, 0.f);
                    hout[(long)rowD * F + col] = __float2bfloat16(v);
                }
            }
        }
    }
}

// ================================================================ pooling (batch sorted)
__global__ __launch_bounds__(128) void pool_kernel(const __hip_bfloat16* __restrict__ h,
                                                   const int* __restrict__ batch,
                                                   float* __restrict__ add_p,
                                                   unsigned* __restrict__ max_p,
                                                   float* __restrict__ cnt, int n) {
    int start = blockIdx.x * 128;
    if (start >= n) return;
    int end = min(start + 128, n);
    int c = threadIdx.x;

    float s = 0.f, mx = 0.f, ct = 0.f;
    int g = batch[start];
    for (int m = start; m < end; ++m) {
        int gm = batch[m];
        if (gm != g) {
            atomicAdd(&add_p[g * F + c], s);
            atomicMax(&max_p[g * F + c], __float_as_uint(mx));
            if (c == 0) atomicAdd(&cnt[g], ct);
            s = 0.f; mx = 0.f; ct = 0.f; g = gm;
        }
        float v = __bfloat162float(h[(long)m * F + c]);
        s += v;
        mx = fmaxf(mx, v);
        ct += 1.f;
    }
    atomicAdd(&add_p[g * F + c], s);
    atomicMax(&max_p[g * F + c], __float_as_uint(mx));
    if (c == 0) atomicAdd(&cnt[g], ct);
}

// ================================================================ head MLP + log_softmax
__global__ __launch_bounds__(128) void head_kernel(const float* __restrict__ add_p,
                                                   const float* __restrict__ cnt,
                                                   const unsigned* __restrict__ max_p,
                                                   const float* __restrict__ W1,
                                                   const float* __restrict__ b1,
                                                   const float* __restrict__ W2,
                                                   const float* __restrict__ b2,
                                                   float* __restrict__ out) {
    int g = blockIdx.x, n = threadIdx.x;
    __shared__ float gv[384];
    float a    = add_p[g * F + n];
    float invc = 1.f / fmaxf(cnt[g], 1.f);
    gv[n]       = a;
    gv[128 + n] = a * invc;
    gv[256 + n] = __uint_as_float(max_p[g * F + n]);
    __syncthreads();

    float acc = b1[n];
    #pragma unroll 8
    for (int k = 0; k < 384; ++k) acc += gv[k] * W1[k * F + n];
    float r = fmaxf(acc, 0.f);

    float l0 = r * W2[n * 2 + 0];
    float l1 = r * W2[n * 2 + 1];
    #pragma unroll
    for (int off = 32; off > 0; off >>= 1) {
        l0 += __shfl_down(l0, off);
        l1 += __shfl_down(l1, off);
    }
    __shared__ float part[4];
    if ((n & 63) == 0) { part[(n >> 6) * 2] = l0; part[(n >> 6) * 2 + 1] = l1; }
    __syncthreads();
    if (n == 0) {
        float L0 = part[0] + part[2] + b2[0];
        float L1 = part[1] + part[3] + b2[1];
        float m  = fmaxf(L0, L1);
        float lse = m + logf(expf(L0 - m) + expf(L1 - m));
        out[g * 2 + 0] = L0 - lse;
        out[g * 2 + 1] = L1 - lse;
    }
}

// ================================================================ launch
extern "C" void kernel_launch(void* const* d_in, const int* in_sizes, int n_in,
                              void* d_out, int out_size, void* d_ws, size_t ws_size,
                              hipStream_t stream) {
    const float* x     = (const float*)d_in[0];
    const int*   ei    = (const int*)d_in[1];
    const int*   batch = (const int*)d_in[2];
    const float* Wl0 = (const float*)d_in[3];
    const float* Wr0 = (const float*)d_in[4];
    const float* b0  = (const float*)d_in[5];
    const float* Wl1 = (const float*)d_in[6];
    const float* Wr1 = (const float*)d_in[7];
    const float* b1  = (const float*)d_in[8];
    const float* Wl2 = (const float*)d_in[9];
    const float* Wr2 = (const float*)d_in[10];
    const float* b2  = (const float*)d_in[11];
    const float* W_lin1 = (const float*)d_in[12];
    const float* b_lin1 = (const float*)d_in[13];
    const float* W_lin2 = (const float*)d_in[14];
    const float* b_lin2 = (const float*)d_in[15];

    const int nE = in_sizes[1] / 2;
    const int* src = ei;
    const int* dst = ei + nE;

    // workspace layout (16B-aligned chunks); rows = N_NODES+1 (sentinel zero row)
    const long ROWS = N_NODES + 16;
    char* p = (char*)d_ws;
    int*   row_ptr = (int*)p;            p += 50048 * 4;
    int*   deg_arr = (int*)p;            p += 50048 * 4;
    unsigned short* csr = (unsigned short*)p;  p += (((long)nE + (long)NB * PADMAX + 63) & ~63L) * 2;
    int*   bh      = (int*)p;            p += ((long)NB * B1 + 16) * 4;
    int*   boff    = (int*)p;            p += ((long)NB * B1 + 16) * 4;
    int*   btot    = (int*)p;            p += 512 * 4;
    int*   bbase   = (int*)p;            p += 512 * 4;
    __hip_bfloat16* xb   = (__hip_bfloat16*)p; p += ROWS * F * 2;
    __hip_bfloat16* aggb = (__hip_bfloat16*)p; p += ROWS * F * 2;
    __hip_bfloat16* h1b  = (__hip_bfloat16*)p; p += ROWS * F * 2;
    __hip_bfloat16* h2b  = (__hip_bfloat16*)p; p += ROWS * F * 2;
    __hip_bfloat16* h3b  = (__hip_bfloat16*)p; p += ROWS * F * 2;
    __hip_bfloat16* Wf   = (__hip_bfloat16*)p; p += 3L * 32768 * 2;
    float* add_p   = (float*)p;          p += NGRAPH * F * 4;
    unsigned* max_p = (unsigned*)p;      p += NGRAPH * F * 4;
    float* cnt     = (float*)p;          p += 256;

    // ebuf (ushort2, 6.4 MB) aliases aggb (dead until first gather, after csr_build)
    ushort2* ebuf = (ushort2*)aggb;

    const int chunk = (nE + B1 - 1) / B1;
    const int gridG = (N_NODES + 63) / 64;
    const int gridW = (N_NODES + 3) / 4;
    const int gridP = (N_NODES + 127) / 128;
    const int gridC = (int)(((long)N_NODES * F / 4 + 255) / 256);

    // ---- CSR build: deterministic multisplit, no global atomics
    bucket_hist <<<B1, 256, 0, stream>>>(dst, bh, nE, chunk);
    scan_blocks <<<NB, 512, 0, stream>>>(bh, boff, btot);
    scan_buckets<<<1,  512, 0, stream>>>(btot, bbase);
    bucket_place<<<B1, 256, 0, stream>>>(src, dst, boff, bbase, ebuf, nE, chunk);
    csr_build   <<<NB, 256, 0, stream>>>(ebuf, bbase, row_ptr, deg_arr, csr, N_NODES);

    // ---- bf16 inputs + sentinel rows + fragment-packed weights
    cvt_kernel<<<gridC, 256, 0, stream>>>(x, xb, (long)N_NODES * F / 4);
    zero_rows<<<1, 64, 0, stream>>>(xb, h1b, h2b);
    wfrag_all<<<48, 256, 0, stream>>>(Wl0, Wr0, Wl1, Wr1, Wl2, Wr2, Wf);

    // ---- layer 0
    gather_kernel<<<gridW, 256, 0, stream>>>(xb, row_ptr, deg_arr, csr, aggb, N_NODES);
    sage_gemm<<<gridG, 256, 0, stream>>>(aggb, xb, Wf, b0, h1b, N_NODES);
    // ---- layer 1
    gather_kernel<<<gridW, 256, 0, stream>>>(h1b, row_ptr, deg_arr, csr, aggb, N_NODES);
    sage_gemm<<<gridG, 256, 0, stream>>>(aggb, h1b, Wf + 32768, b1, h2b, N_NODES);
    // ---- layer 2
    gather_kernel<<<gridW, 256, 0, stream>>>(h2b, row_ptr, deg_arr, csr, aggb, N_NODES);
    sage_gemm<<<gridG, 256, 0, stream>>>(aggb, h2b, Wf + 65536, b2, h3b, N_NODES);

    // ---- pooling
    hipMemsetAsync(add_p, 0, (NGRAPH * F * 2 + NGRAPH) * sizeof(float), stream);
    pool_kernel<<<gridP, 128, 0, stream>>>(h3b, batch, add_p, max_p, cnt, N_NODES);

    // ---- head
    head_kernel<<<NGRAPH, 128, 0, stream>>>(add_p, cnt, max_p,
                                            W_lin1, b_lin1, W_lin2, b_lin2,
                                            (float*)d_out);
}